// Round 2
// baseline (308.574 us; speedup 1.0000x reference)
//
#include <hip/hip_runtime.h>

typedef unsigned short u16;
typedef unsigned int u32;
typedef short bf16x8 __attribute__((ext_vector_type(8)));
typedef float f32x4 __attribute__((ext_vector_type(4)));

#define D_MODEL 1024
#define NHEADS 16
#define DHEAD 64
#define BATCH 2
#define SEQ 2048
#define NROWS (BATCH * SEQ) /* 4096 */

static __device__ __forceinline__ u16 f2bf(float f) {
  u32 x = __float_as_uint(f);
  x += 0x7fffu + ((x >> 16) & 1u); // RNE
  return (u16)(x >> 16);
}

// global -> LDS direct (16B/lane). LDS dest is WAVE-UNIFORM base + lane*16 (m104/m108).
#define GLL16(gp, lp)                                             \
  __builtin_amdgcn_global_load_lds(                               \
      (const __attribute__((address_space(1))) u32*)(gp),         \
      (__attribute__((address_space(3))) u32*)(lp), 16, 0, 0)

__global__ __launch_bounds__(256) void castk(const float* __restrict__ in,
                                             u16* __restrict__ out, int n4) {
  int i = blockIdx.x * 256 + threadIdx.x;
  if (i >= n4) return;
  float4 v = ((const float4*)in)[i];
  u32 lo = (u32)f2bf(v.x) | ((u32)f2bf(v.y) << 16);
  u32 hi = (u32)f2bf(v.z) | ((u32)f2bf(v.w) << 16);
  ((uint2*)out)[i] = make_uint2(lo, hi);
}

// C[M,N] = A[M,K] * Bw[N,K]^T + bias ; all bf16 in, fp32 accum.
// m97 structure: 128x128 tile, BK=32, 4 waves (2x2), 4x4 16x16x32 MFMA per wave.
template <int OUTF32>
__device__ __forceinline__ void gemm_core(const u16* __restrict__ A,
                                          const u16* __restrict__ Bw,
                                          const float* __restrict__ bias,
                                          u16* __restrict__ ob,
                                          float* __restrict__ of,
                                          int bm, int bn) {
  constexpr int K = 1024, N = 1024;
  __shared__ __attribute__((aligned(16))) u16 As[128 * 32];
  __shared__ __attribute__((aligned(16))) u16 Bs[128 * 32];
  const int tx = threadIdx.x;
  const int w = tx >> 6, lane = tx & 63;
  const int wm = w >> 1, wn = w & 1;
  const int c = lane & 15, g = lane >> 4;
  f32x4 acc[4][4];
  for (int m = 0; m < 4; ++m)
    for (int n = 0; n < 4; ++n) acc[m][n] = {0.f, 0.f, 0.f, 0.f};
  const int srow = w * 16 + (lane >> 2); // staging row within 64-row half
  const int sck = (lane & 3) * 8;        // staging K-chunk (8 elems)
  for (int k0 = 0; k0 < K; k0 += 32) {
    for (int m = 0; m < 2; ++m) {
      GLL16(A + (size_t)(bm + m * 64 + srow) * K + k0 + sck,
            (char*)As + m * 4096 + w * 1024);
      GLL16(Bw + (size_t)(bn + m * 64 + srow) * K + k0 + sck,
            (char*)Bs + m * 4096 + w * 1024);
    }
    __syncthreads(); // drains vmcnt -> staged data visible
    bf16x8 af[4], bf_[4];
    for (int m = 0; m < 4; ++m)
      af[m] = *(const bf16x8*)(As + (wm * 64 + m * 16 + c) * 32 + g * 8);
    for (int n = 0; n < 4; ++n)
      bf_[n] = *(const bf16x8*)(Bs + (wn * 64 + n * 16 + c) * 32 + g * 8);
    for (int m = 0; m < 4; ++m)
      for (int n = 0; n < 4; ++n)
        acc[m][n] = __builtin_amdgcn_mfma_f32_16x16x32_bf16(af[m], bf_[n],
                                                            acc[m][n], 0, 0, 0);
    __syncthreads(); // compute done before next-tile staging
  }
  // D layout: row = 4*(lane>>4)+r, col = lane&15 (m89/m91 verified)
  for (int n = 0; n < 4; ++n) {
    const int col = bn + wn * 64 + n * 16 + c;
    const float bv = bias[col];
    for (int m = 0; m < 4; ++m)
      for (int r = 0; r < 4; ++r) {
        const int row = bm + wm * 64 + m * 16 + g * 4 + r;
        float v = acc[m][n][r] + bv;
        if (OUTF32)
          of[(size_t)row * N + col] = v;
        else
          ob[(size_t)row * N + col] = f2bf(v);
      }
  }
}

__global__ __launch_bounds__(256) void gemm_qkv(const u16* __restrict__ xb,
                                                const u16* __restrict__ wq,
                                                const u16* __restrict__ wk,
                                                const u16* __restrict__ wv,
                                                const float* __restrict__ bq,
                                                const float* __restrict__ bk,
                                                const float* __restrict__ bv,
                                                u16* __restrict__ q,
                                                u16* __restrict__ k,
                                                u16* __restrict__ v) {
  const int z = blockIdx.z;
  const u16* W = (z == 0) ? wq : (z == 1) ? wk : wv;
  const float* bi = (z == 0) ? bq : (z == 1) ? bk : bv;
  u16* o = (z == 0) ? q : (z == 1) ? k : v;
  gemm_core<0>(xb, W, bi, o, nullptr, blockIdx.y * 128, blockIdx.x * 128);
}

__global__ __launch_bounds__(256) void gemm_o(const u16* __restrict__ yb,
                                              const u16* __restrict__ wo,
                                              const float* __restrict__ bo,
                                              float* __restrict__ out) {
  gemm_core<1>(yb, wo, bo, nullptr, out, blockIdx.y * 128, blockIdx.x * 128);
}

// Flash attention w/ ALiBi + causal. Block: 64 q-rows, 4 waves (16 q-rows each).
// Q/K staged swizzled (global-source pre-swizzle chunk^=row&7, since
// global_load_lds dest is linear; rule #21 both-sides-or-neither);
// V staged linear, read via scalar u16 (tr_b16 candidate later).
__global__ __launch_bounds__(256) void attn(const u16* __restrict__ qb,
                                            const u16* __restrict__ kb,
                                            const u16* __restrict__ vbuf,
                                            u16* __restrict__ yb) {
  __shared__ __attribute__((aligned(16))) u16 Qs[64 * 64];
  __shared__ __attribute__((aligned(16))) u16 Ks[64 * 64];
  __shared__ __attribute__((aligned(16))) u16 Vs[64 * 64];
  __shared__ __attribute__((aligned(16))) u16 Ps[4 * 16 * 64];
  const int tx = threadIdx.x;
  const int w = tx >> 6, lane = tx & 63;
  const int c = lane & 15, g = lane >> 4;
  const int qi = blockIdx.x, bh = blockIdx.y;
  const int b = bh >> 4, h = bh & 15;
  const int q0 = qi * 64;
  const size_t rb = (size_t)b * SEQ;
  const float slope = exp2f(-0.5f * (float)(h + 1)); // H=16 pow2 slopes

  const int strow = w * 8 + (lane >> 3); // staging row within 32-row half
  const int stck = lane & 7;             // staging chunk (8 elems of 8)

  for (int m = 0; m < 2; ++m) { // stage Q once, swizzled
    int row = m * 32 + strow;
    GLL16(qb + (rb + q0 + row) * D_MODEL + h * DHEAD + ((stck ^ (row & 7)) * 8),
          (char*)Qs + m * 4096 + w * 1024);
  }

  float mrun[4], lsum[4];
  f32x4 acc[4];
  for (int r = 0; r < 4; ++r) { mrun[r] = -1e30f; lsum[r] = 0.f; }
  for (int d = 0; d < 4; ++d) acc[d] = {0.f, 0.f, 0.f, 0.f};

  for (int kt = 0; kt <= qi; ++kt) {
    __syncthreads(); // prev iter reads done before restage
    for (int m = 0; m < 2; ++m) {
      int row = m * 32 + strow;
      GLL16(kb + (rb + kt * 64 + row) * D_MODEL + h * DHEAD +
                ((stck ^ (row & 7)) * 8),
            (char*)Ks + m * 4096 + w * 1024);
      GLL16(vbuf + (rb + kt * 64 + row) * D_MODEL + h * DHEAD + stck * 8,
            (char*)Vs + m * 4096 + w * 1024);
    }
    __syncthreads();

    // S = Q K^T : A-frag rows = this wave's 16 q, B-frag rows = k-cols
    bf16x8 aq[2];
    for (int ks = 0; ks < 2; ++ks)
      aq[ks] = *(const bf16x8*)((const char*)Qs + (w * 16 + c) * 128 +
                                ((ks * 64 + g * 16) ^ ((c & 7) << 4)));
    f32x4 sc[4];
    for (int n = 0; n < 4; ++n) {
      sc[n] = {0.f, 0.f, 0.f, 0.f};
      for (int ks = 0; ks < 2; ++ks) {
        bf16x8 bk = *(const bf16x8*)((const char*)Ks + (n * 16 + c) * 128 +
                                     ((ks * 64 + g * 16) ^ ((c & 7) << 4)));
        sc[n] = __builtin_amdgcn_mfma_f32_16x16x32_bf16(aq[ks], bk, sc[n], 0, 0, 0);
      }
    }

    // online softmax; lane holds rows 4g+r, cols n*16+c
    float p[4][4];
    for (int r = 0; r < 4; ++r) {
      const int qidx = q0 + w * 16 + g * 4 + r;
      float srow_[4];
      float rmax = -1e30f;
      for (int n = 0; n < 4; ++n) {
        const int kidx = kt * 64 + n * 16 + c;
        float s = sc[n][r] * 0.125f + slope * (float)(kidx - qidx);
        if (kidx > qidx) s = -1e30f; // causal
        srow_[n] = s;
        rmax = fmaxf(rmax, s);
      }
      for (int off = 1; off < 16; off <<= 1)
        rmax = fmaxf(rmax, __shfl_xor(rmax, off));
      const float mn = fmaxf(mrun[r], rmax);
      const float corr = __expf(mrun[r] - mn);
      mrun[r] = mn;
      float rsum = 0.f;
      for (int n = 0; n < 4; ++n) {
        float pv = __expf(srow_[n] - mn);
        p[n][r] = pv;
        rsum += pv;
      }
      for (int off = 1; off < 16; off <<= 1) rsum += __shfl_xor(rsum, off);
      lsum[r] = lsum[r] * corr + rsum;
      for (int d = 0; d < 4; ++d) acc[d][r] *= corr;
    }

    // P (D-layout) -> LDS (bf16, row-XOR swizzle) -> A-frag layout
    for (int n = 0; n < 4; ++n)
      for (int r = 0; r < 4; ++r) {
        const int row = g * 4 + r;
        *(u16*)((char*)Ps + w * 2048 + row * 128 +
                (((n * 16 + c) * 2) ^ ((row & 7) << 4))) = f2bf(p[n][r]);
      }

    // O += P V : A-frag from Ps (b128, swizzled), B-frag from Vs (8x scalar)
    for (int ks = 0; ks < 2; ++ks) {
      bf16x8 pa = *(const bf16x8*)((const char*)Ps + w * 2048 + c * 128 +
                                   ((ks * 64 + g * 16) ^ ((c & 7) << 4)));
      for (int d = 0; d < 4; ++d) {
        bf16x8 vb_;
        for (int j = 0; j < 8; ++j)
          vb_[j] = (short)Vs[(ks * 32 + g * 8 + j) * 64 + d * 16 + c];
        acc[d] = __builtin_amdgcn_mfma_f32_16x16x32_bf16(pa, vb_, acc[d], 0, 0, 0);
      }
    }
  }

  for (int d = 0; d < 4; ++d)
    for (int r = 0; r < 4; ++r) {
      const int qlocal = w * 16 + g * 4 + r;
      float o = acc[d][r] / lsum[r];
      yb[(rb + q0 + qlocal) * D_MODEL + h * DHEAD + d * 16 + c] = f2bf(o);
    }
}

extern "C" void kernel_launch(void* const* d_in, const int* in_sizes, int n_in,
                              void* d_out, int out_size, void* d_ws,
                              size_t ws_size, hipStream_t stream) {
  const float* x = (const float*)d_in[0];
  const float* Wq = (const float*)d_in[1];
  const float* bq = (const float*)d_in[2];
  const float* Wk = (const float*)d_in[3];
  const float* bk = (const float*)d_in[4];
  const float* Wv = (const float*)d_in[5];
  const float* bv = (const float*)d_in[6];
  const float* Wo = (const float*)d_in[7];
  const float* bo = (const float*)d_in[8];
  float* out = (float*)d_out;

  // workspace layout (40 MB total; yb aliases xb — x dead after gemm_qkv)
  char* ws = (char*)d_ws;
  u16* xb = (u16*)(ws + (size_t)0);          // 8 MB  4096x1024 bf16
  u16* wqb = (u16*)(ws + ((size_t)8 << 20)); // 2 MB each
  u16* wkb = (u16*)(ws + ((size_t)10 << 20));
  u16* wvb = (u16*)(ws + ((size_t)12 << 20));
  u16* wob = (u16*)(ws + ((size_t)14 << 20));
  u16* qb = (u16*)(ws + ((size_t)16 << 20)); // 8 MB each
  u16* kb = (u16*)(ws + ((size_t)24 << 20));
  u16* vb = (u16*)(ws + ((size_t)32 << 20));
  u16* yb = xb; // reuse: attn writes yb strictly after gemm_qkv reads xb

  castk<<<4096, 256, 0, stream>>>(x, xb, NROWS * D_MODEL / 4);
  castk<<<1024, 256, 0, stream>>>(Wq, wqb, D_MODEL * D_MODEL / 4);
  castk<<<1024, 256, 0, stream>>>(Wk, wkb, D_MODEL * D_MODEL / 4);
  castk<<<1024, 256, 0, stream>>>(Wv, wvb, D_MODEL * D_MODEL / 4);
  castk<<<1024, 256, 0, stream>>>(Wo, wob, D_MODEL * D_MODEL / 4);

  gemm_qkv<<<dim3(8, 32, 3), 256, 0, stream>>>(xb, wqb, wkb, wvb, bq, bk, bv,
                                               qb, kb, vb);
  attn<<<dim3(32, 32, 1), 256, 0, stream>>>(qb, kb, vb, yb);
  gemm_o<<<dim3(8, 32, 1), 256, 0, stream>>>(yb, wob, bo, out);
}

// Round 7
// 245.798 us; speedup vs baseline: 1.2554x; 1.2554x over previous
//
#include <hip/hip_runtime.h>

typedef unsigned short u16;
typedef unsigned int u32;
typedef short bf16x8 __attribute__((ext_vector_type(8)));
typedef float f32x4 __attribute__((ext_vector_type(4)));
typedef u16 u16x4 __attribute__((ext_vector_type(4)));

#define D_MODEL 1024
#define NHEADS 16
#define DHEAD 64
#define BATCH 2
#define SEQ 2048
#define NROWS (BATCH * SEQ) /* 4096 */
#define NTILES (SEQ / 64)   /* 32 */

static __device__ __forceinline__ u16 f2bf(float f) {
  u32 x = __float_as_uint(f);
  x += 0x7fffu + ((x >> 16) & 1u); // RNE
  return (u16)(x >> 16);
}

// global -> LDS direct (16B/lane). LDS dest is WAVE-UNIFORM base + lane*16 (m104/m108).
#define GLL16(gp, lp)                                             \
  __builtin_amdgcn_global_load_lds(                               \
      (const __attribute__((address_space(1))) u32*)(gp),         \
      (__attribute__((address_space(3))) u32*)(lp), 16, 0, 0)

__global__ __launch_bounds__(256) void castk(const float* __restrict__ in,
                                             u16* __restrict__ out, int n4) {
  int i = blockIdx.x * 256 + threadIdx.x;
  if (i >= n4) return;
  float4 v = ((const float4*)in)[i];
  u32 lo = (u32)f2bf(v.x) | ((u32)f2bf(v.y) << 16);
  u32 hi = (u32)f2bf(v.z) | ((u32)f2bf(v.w) << 16);
  ((uint2*)out)[i] = make_uint2(lo, hi);
}

// fused weight casts: z selects which W
__global__ __launch_bounds__(256) void castw(const float* __restrict__ w0,
                                             const float* __restrict__ w1,
                                             const float* __restrict__ w2,
                                             const float* __restrict__ w3,
                                             u16* __restrict__ o0,
                                             u16* __restrict__ o1,
                                             u16* __restrict__ o2,
                                             u16* __restrict__ o3) {
  const int z = blockIdx.z;
  const float* in = (z == 0) ? w0 : (z == 1) ? w1 : (z == 2) ? w2 : w3;
  u16* out = (z == 0) ? o0 : (z == 1) ? o1 : (z == 2) ? o2 : o3;
  int i = blockIdx.x * 256 + threadIdx.x;
  float4 v = ((const float4*)in)[i];
  u32 lo = (u32)f2bf(v.x) | ((u32)f2bf(v.y) << 16);
  u32 hi = (u32)f2bf(v.z) | ((u32)f2bf(v.w) << 16);
  ((uint2*)out)[i] = make_uint2(lo, hi);
}

// C[M,N] = A[M,K] * Bw[N,K]^T + bias ; all bf16 in, fp32 accum.
// m97 structure: 128x128 tile, BK=32, 4 waves (2x2), 4x4 16x16x32 MFMA per wave.
// MODE: 0 = bf16 row-major out, 1 = f32 row-major out,
//       2 = bf16 per-head TRANSPOSED out: vt[((b*16+h)*64+dh)][s] (for V)
template <int MODE>
__device__ __forceinline__ void gemm_core(const u16* __restrict__ A,
                                          const u16* __restrict__ Bw,
                                          const float* __restrict__ bias,
                                          u16* __restrict__ ob,
                                          float* __restrict__ of,
                                          int bm, int bn) {
  constexpr int K = 1024, N = 1024;
  __shared__ __attribute__((aligned(16))) u16 As[128 * 32];
  __shared__ __attribute__((aligned(16))) u16 Bs[128 * 32];
  const int tx = threadIdx.x;
  const int w = tx >> 6, lane = tx & 63;
  const int wm = w >> 1, wn = w & 1;
  const int c = lane & 15, g = lane >> 4;
  f32x4 acc[4][4];
  for (int m = 0; m < 4; ++m)
    for (int n = 0; n < 4; ++n) acc[m][n] = {0.f, 0.f, 0.f, 0.f};
  const int srow = w * 16 + (lane >> 2); // staging row within 64-row half
  const int sck = (lane & 3) * 8;        // staging K-chunk (8 elems)
  for (int k0 = 0; k0 < K; k0 += 32) {
    for (int m = 0; m < 2; ++m) {
      GLL16(A + (size_t)(bm + m * 64 + srow) * K + k0 + sck,
            (char*)As + m * 4096 + w * 1024);
      GLL16(Bw + (size_t)(bn + m * 64 + srow) * K + k0 + sck,
            (char*)Bs + m * 4096 + w * 1024);
    }
    __syncthreads(); // drains vmcnt -> staged data visible
    bf16x8 af[4], bf_[4];
    for (int m = 0; m < 4; ++m)
      af[m] = *(const bf16x8*)(As + (wm * 64 + m * 16 + c) * 32 + g * 8);
    for (int n = 0; n < 4; ++n)
      bf_[n] = *(const bf16x8*)(Bs + (wn * 64 + n * 16 + c) * 32 + g * 8);
    for (int m = 0; m < 4; ++m)
      for (int n = 0; n < 4; ++n)
        acc[m][n] = __builtin_amdgcn_mfma_f32_16x16x32_bf16(af[m], bf_[n],
                                                            acc[m][n], 0, 0, 0);
    __syncthreads(); // compute done before next-tile staging
  }
  // D layout: row = 4*(lane>>4)+r, col = lane&15 (m89/m91 verified)
  for (int n = 0; n < 4; ++n) {
    const int col = bn + wn * 64 + n * 16 + c;
    const float bv = bias[col];
    for (int m = 0; m < 4; ++m) {
      if (MODE == 2) {
        // rows s = base..base+3 are consecutive -> pack one 8B store into
        // vt[((b*16+h)*64+dh)][s], b = s>>11, h = col>>6, dh = col&63
        const int rs = bm + wm * 64 + m * 16 + g * 4; // 4-aligned
        u16x4 pk;
        for (int r = 0; r < 4; ++r) pk[r] = f2bf(acc[m][n][r] + bv);
        const size_t vrow = (size_t)((rs >> 11) * NHEADS + (col >> 6)) * DHEAD +
                            (col & 63);
        *(u16x4*)(ob + vrow * SEQ + (rs & 2047)) = pk;
      } else {
        for (int r = 0; r < 4; ++r) {
          const int row = bm + wm * 64 + m * 16 + g * 4 + r;
          float v = acc[m][n][r] + bv;
          if (MODE == 1)
            of[(size_t)row * N + col] = v;
          else
            ob[(size_t)row * N + col] = f2bf(v);
        }
      }
    }
  }
}

__global__ __launch_bounds__(256) void gemm_qkv(const u16* __restrict__ xb,
                                                const u16* __restrict__ wq,
                                                const u16* __restrict__ wk,
                                                const float* __restrict__ bq,
                                                const float* __restrict__ bk,
                                                u16* __restrict__ q,
                                                u16* __restrict__ k) {
  const int z = blockIdx.z;
  const u16* W = (z == 0) ? wq : wk;
  const float* bi = (z == 0) ? bq : bk;
  u16* o = (z == 0) ? q : k;
  gemm_core<0>(xb, W, bi, o, nullptr, blockIdx.y * 128, blockIdx.x * 128);
}

__global__ __launch_bounds__(256) void gemm_v(const u16* __restrict__ xb,
                                              const u16* __restrict__ wv,
                                              const float* __restrict__ bv,
                                              u16* __restrict__ vt) {
  gemm_core<2>(xb, wv, bv, vt, nullptr, blockIdx.y * 128, blockIdx.x * 128);
}

__global__ __launch_bounds__(256) void gemm_o(const u16* __restrict__ yb,
                                              const u16* __restrict__ wo,
                                              const float* __restrict__ bo,
                                              float* __restrict__ out) {
  gemm_core<1>(yb, wo, bo, nullptr, out, blockIdx.y * 128, blockIdx.x * 128);
}

// Flash attention w/ ALiBi + causal.
// Triangle-paired q-tiles (block bx does qi=bx then qi=31-bx, 33 tile-iters
// each), double-buffered K/V with issue-before-compute prefetch (one
// barrier/iter), exp2-folded softmax. V consumed from per-head TRANSPOSED
// global layout vt[(b*16+h)*64+dh][s]: staged like K (pre-swizzled source,
// linear LDS), PV B-frag = single swizzled ds_read_b128 (replaces 64 scalar
// ds_read_u16 of the round-2 baseline).
__global__ __launch_bounds__(256) void attn(const u16* __restrict__ qb,
                                            const u16* __restrict__ kb,
                                            const u16* __restrict__ vt,
                                            u16* __restrict__ yb) {
  __shared__ __attribute__((aligned(16))) u16 Qs[64 * 64];
  __shared__ __attribute__((aligned(16))) u16 Ks[2 * 64 * 64];
  __shared__ __attribute__((aligned(16))) u16 Vs[2 * 64 * 64]; // [dh][k]
  __shared__ __attribute__((aligned(16))) u16 Ps[4 * 16 * 64];
  const int tx = threadIdx.x;
  const int w = tx >> 6, lane = tx & 63;
  const int c = lane & 15, g = lane >> 4;
  const int bh = blockIdx.y;
  const int b = bh >> 4, h = bh & 15;
  const size_t rb = (size_t)b * SEQ;
  const size_t vtb = (size_t)bh * DHEAD; // vt row base for this (b,h)
  // base-2 folded constants: p = exp2(sc*S2 + slope2*(kidx-qidx) - m2)
  const float slope2 = exp2f(-0.5f * (float)(h + 1)) * 1.44269504f;
  const float S2 = 0.125f * 1.44269504f;

  const int strow = w * 8 + (lane >> 3); // staging row within 32-row half
  const int stck = lane & 7;             // staging chunk (8 elems of 8)

  for (int pass = 0; pass < 2; ++pass) {
    const int qi = pass ? (NTILES - 1 - blockIdx.x) : blockIdx.x;
    const int q0 = qi * 64;
    if (pass) __syncthreads(); // protect Qs/Ks/Vs reuse across passes

    // stage Q (swizzled) and K/V tile 0 into buf 0
    for (int m = 0; m < 2; ++m) {
      int row = m * 32 + strow;
      GLL16(qb + (rb + q0 + row) * D_MODEL + h * DHEAD +
                ((stck ^ (row & 7)) * 8),
            (char*)Qs + m * 4096 + w * 1024);
      GLL16(kb + (rb + row) * D_MODEL + h * DHEAD + ((stck ^ (row & 7)) * 8),
            (char*)Ks + m * 4096 + w * 1024);
      // V: row = dh, cols = k-window; same swizzle pattern as K
      GLL16(vt + (vtb + row) * SEQ + ((stck ^ (row & 7)) * 8),
            (char*)Vs + m * 4096 + w * 1024);
    }

    float mrun[4], lsum[4];
    f32x4 acc[4];
    for (int r = 0; r < 4; ++r) { mrun[r] = -1e30f; lsum[r] = 0.f; }
    for (int d = 0; d < 4; ++d) acc[d] = {0.f, 0.f, 0.f, 0.f};
    const float qrow[4] = {(float)(q0 + w * 16 + g * 4 + 0),
                           (float)(q0 + w * 16 + g * 4 + 1),
                           (float)(q0 + w * 16 + g * 4 + 2),
                           (float)(q0 + w * 16 + g * 4 + 3)};
    const int qrowi = q0 + w * 16 + g * 4;

    int cur = 0;
    for (int kt = 0; kt <= qi; ++kt) {
      __syncthreads(); // drains own GLL16s -> buf[cur] (and Qs) ready
      if (kt < qi) {   // prefetch next tile into buf^1; drain at NEXT barrier
        for (int m = 0; m < 2; ++m) {
          int row = m * 32 + strow;
          GLL16(kb + (rb + (kt + 1) * 64 + row) * D_MODEL + h * DHEAD +
                    ((stck ^ (row & 7)) * 8),
                (char*)Ks + (cur ^ 1) * 8192 + m * 4096 + w * 1024);
          GLL16(vt + (vtb + row) * SEQ + (kt + 1) * 64 +
                    ((stck ^ (row & 7)) * 8),
                (char*)Vs + (cur ^ 1) * 8192 + m * 4096 + w * 1024);
        }
      }

      // S = Q K^T
      bf16x8 aq[2];
      for (int ks = 0; ks < 2; ++ks)
        aq[ks] = *(const bf16x8*)((const char*)Qs + (w * 16 + c) * 128 +
                                  ((ks * 64 + g * 16) ^ ((c & 7) << 4)));
      f32x4 sc[4];
      for (int n = 0; n < 4; ++n) {
        sc[n] = {0.f, 0.f, 0.f, 0.f};
        for (int ks = 0; ks < 2; ++ks) {
          bf16x8 bk = *(const bf16x8*)((const char*)Ks + cur * 8192 +
                                       (n * 16 + c) * 128 +
                                       ((ks * 64 + g * 16) ^ ((c & 7) << 4)));
          sc[n] =
              __builtin_amdgcn_mfma_f32_16x16x32_bf16(aq[ks], bk, sc[n], 0, 0, 0);
        }
      }

      // online softmax (base-2); lane holds rows 4g+r, cols n*16+c
      const int kbase = kt * 64 + c;
      const bool diag = (kt == qi); // only diagonal tile has masked entries
      float p[4][4];
      for (int r = 0; r < 4; ++r) {
        const float base = slope2 * ((float)kbase - qrow[r]);
        float srow_[4];
        float rmax = -1e30f;
        for (int n = 0; n < 4; ++n) {
          float s = fmaf(sc[n][r], S2, base + slope2 * (float)(n * 16));
          if (diag && (kbase + n * 16 > qrowi + r)) s = -1e30f;
          srow_[n] = s;
          rmax = fmaxf(rmax, s);
        }
        for (int off = 1; off < 16; off <<= 1)
          rmax = fmaxf(rmax, __shfl_xor(rmax, off));
        const float mn = fmaxf(mrun[r], rmax);
        const float corr = exp2f(mrun[r] - mn);
        mrun[r] = mn;
        float rsum = 0.f;
        for (int n = 0; n < 4; ++n) {
          float pv = exp2f(srow_[n] - mn);
          p[n][r] = pv;
          rsum += pv;
        }
        for (int off = 1; off < 16; off <<= 1) rsum += __shfl_xor(rsum, off);
        lsum[r] = lsum[r] * corr + rsum;
        for (int d = 0; d < 4; ++d) acc[d][r] *= corr;
      }

      // P (D-layout) -> LDS (bf16, row-XOR swizzle) -> A-frag layout
      for (int n = 0; n < 4; ++n)
        for (int r = 0; r < 4; ++r) {
          const int row = g * 4 + r;
          *(u16*)((char*)Ps + w * 2048 + row * 128 +
                  (((n * 16 + c) * 2) ^ ((row & 7) << 4))) = f2bf(p[n][r]);
        }

      // O += P V : A-frag from Ps, B-frag from Vs[dh][k] — both swizzled b128
      for (int ks = 0; ks < 2; ++ks) {
        bf16x8 pa = *(const bf16x8*)((const char*)Ps + w * 2048 + c * 128 +
                                     ((ks * 64 + g * 16) ^ ((c & 7) << 4)));
        for (int d = 0; d < 4; ++d) {
          bf16x8 vb_ = *(const bf16x8*)((const char*)Vs + cur * 8192 +
                                        (d * 16 + c) * 128 +
                                        ((ks * 64 + g * 16) ^ ((c & 7) << 4)));
          acc[d] = __builtin_amdgcn_mfma_f32_16x16x32_bf16(pa, vb_, acc[d], 0, 0, 0);
        }
      }
      cur ^= 1;
    }

    for (int d = 0; d < 4; ++d)
      for (int r = 0; r < 4; ++r) {
        const int qlocal = w * 16 + g * 4 + r;
        float o = acc[d][r] / lsum[r];
        yb[(rb + q0 + qlocal) * D_MODEL + h * DHEAD + d * 16 + c] = f2bf(o);
      }
  }
}

extern "C" void kernel_launch(void* const* d_in, const int* in_sizes, int n_in,
                              void* d_out, int out_size, void* d_ws,
                              size_t ws_size, hipStream_t stream) {
  const float* x = (const float*)d_in[0];
  const float* Wq = (const float*)d_in[1];
  const float* bq = (const float*)d_in[2];
  const float* Wk = (const float*)d_in[3];
  const float* bk = (const float*)d_in[4];
  const float* Wv = (const float*)d_in[5];
  const float* bv = (const float*)d_in[6];
  const float* Wo = (const float*)d_in[7];
  const float* bo = (const float*)d_in[8];
  float* out = (float*)d_out;

  // workspace layout (40 MB total; yb aliases xb — x dead after projections)
  char* ws = (char*)d_ws;
  u16* xb = (u16*)(ws + (size_t)0);          // 8 MB  4096x1024 bf16
  u16* wqb = (u16*)(ws + ((size_t)8 << 20)); // 2 MB each
  u16* wkb = (u16*)(ws + ((size_t)10 << 20));
  u16* wvb = (u16*)(ws + ((size_t)12 << 20));
  u16* wob = (u16*)(ws + ((size_t)14 << 20));
  u16* qb = (u16*)(ws + ((size_t)16 << 20)); // 8 MB each
  u16* kb = (u16*)(ws + ((size_t)24 << 20));
  u16* vtb = (u16*)(ws + ((size_t)32 << 20)); // 8 MB, [(b*16+h)*64+dh][2048]
  u16* yb = xb; // reuse: attn writes yb strictly after projections read xb

  castk<<<4096, 256, 0, stream>>>(x, xb, NROWS * D_MODEL / 4);
  castw<<<dim3(1024, 1, 4), 256, 0, stream>>>(Wq, Wk, Wv, Wo, wqb, wkb, wvb,
                                              wob);

  gemm_qkv<<<dim3(8, 32, 2), 256, 0, stream>>>(xb, wqb, wkb, bq, bk, qb, kb);
  gemm_v<<<dim3(8, 32, 1), 256, 0, stream>>>(xb, wvb, bv, vtb);
  attn<<<dim3(NTILES / 2, 32, 1), 256, 0, stream>>>(qb, kb, vtb, yb);
  gemm_o<<<dim3(8, 32, 1), 256, 0, stream>>>(yb, wob, bo, out);
}

// Round 8
// 228.085 us; speedup vs baseline: 1.3529x; 1.0777x over previous
//
#include <hip/hip_runtime.h>

typedef unsigned short u16;
typedef unsigned int u32;
typedef short bf16x8 __attribute__((ext_vector_type(8)));
typedef float f32x4 __attribute__((ext_vector_type(4)));
typedef u16 u16x4 __attribute__((ext_vector_type(4)));

#define D_MODEL 1024
#define NHEADS 16
#define DHEAD 64
#define BATCH 2
#define SEQ 2048
#define NROWS (BATCH * SEQ) /* 4096 */
#define NTILES (SEQ / 64)   /* 32 */

static __device__ __forceinline__ u16 f2bf(float f) {
  u32 x = __float_as_uint(f);
  x += 0x7fffu + ((x >> 16) & 1u); // RNE
  return (u16)(x >> 16);
}

// global -> LDS direct (16B/lane). LDS dest is WAVE-UNIFORM base + lane*16 (m104/m108).
#define GLL16(gp, lp)                                             \
  __builtin_amdgcn_global_load_lds(                               \
      (const __attribute__((address_space(1))) u32*)(gp),         \
      (__attribute__((address_space(3))) u32*)(lp), 16, 0, 0)

__global__ __launch_bounds__(256) void castk(const float* __restrict__ in,
                                             u16* __restrict__ out, int n4) {
  int i = blockIdx.x * 256 + threadIdx.x;
  if (i >= n4) return;
  float4 v = ((const float4*)in)[i];
  u32 lo = (u32)f2bf(v.x) | ((u32)f2bf(v.y) << 16);
  u32 hi = (u32)f2bf(v.z) | ((u32)f2bf(v.w) << 16);
  ((uint2*)out)[i] = make_uint2(lo, hi);
}

// fused weight casts: z selects which W
__global__ __launch_bounds__(256) void castw(const float* __restrict__ w0,
                                             const float* __restrict__ w1,
                                             const float* __restrict__ w2,
                                             const float* __restrict__ w3,
                                             u16* __restrict__ o0,
                                             u16* __restrict__ o1,
                                             u16* __restrict__ o2,
                                             u16* __restrict__ o3) {
  const int z = blockIdx.z;
  const float* in = (z == 0) ? w0 : (z == 1) ? w1 : (z == 2) ? w2 : w3;
  u16* out = (z == 0) ? o0 : (z == 1) ? o1 : (z == 2) ? o2 : o3;
  int i = blockIdx.x * 256 + threadIdx.x;
  float4 v = ((const float4*)in)[i];
  u32 lo = (u32)f2bf(v.x) | ((u32)f2bf(v.y) << 16);
  u32 hi = (u32)f2bf(v.z) | ((u32)f2bf(v.w) << 16);
  ((uint2*)out)[i] = make_uint2(lo, hi);
}

// C[M,N] = A[M,K] * Bw[N,K]^T + bias ; all bf16 in, fp32 accum.
// 128x128 tile, BK=32, 4 waves (2x2), 4x4 16x16x32 MFMA per wave.
// 2-phase single-barrier prefetch double-buffer (mirrors the validated attn
// loop): sync -> stage(next, buf^1) -> compute(buf). Own-wave GLL16s drain at
// the wave's own barrier entry (vmcnt(0) before s_barrier).
// MODE: 0 = bf16 row-major out, 1 = f32 row-major out,
//       2 = bf16 per-head TRANSPOSED out: vt[((b*16+h)*64+dh)][s] (for V)
template <int MODE>
__device__ __forceinline__ void gemm_core(const u16* __restrict__ A,
                                          const u16* __restrict__ Bw,
                                          const float* __restrict__ bias,
                                          u16* __restrict__ ob,
                                          float* __restrict__ of,
                                          int bm, int bn) {
  constexpr int K = 1024, N = 1024;
  __shared__ __attribute__((aligned(16))) u16 As[2][128 * 32];
  __shared__ __attribute__((aligned(16))) u16 Bs[2][128 * 32];
  const int tx = threadIdx.x;
  const int w = tx >> 6, lane = tx & 63;
  const int wm = w >> 1, wn = w & 1;
  const int c = lane & 15, g = lane >> 4;
  f32x4 acc[4][4];
  for (int m = 0; m < 4; ++m)
    for (int n = 0; n < 4; ++n) acc[m][n] = {0.f, 0.f, 0.f, 0.f};
  const int srow = w * 16 + (lane >> 2); // staging row within 64-row half
  const int sck = (lane & 3) * 8;        // staging K-chunk (8 elems)
  // prologue: stage K-step 0 into buf 0
  for (int m = 0; m < 2; ++m) {
    GLL16(A + (size_t)(bm + m * 64 + srow) * K + sck,
          (char*)As[0] + m * 4096 + w * 1024);
    GLL16(Bw + (size_t)(bn + m * 64 + srow) * K + sck,
          (char*)Bs[0] + m * 4096 + w * 1024);
  }
  int cur = 0;
  for (int k0 = 0; k0 < K; k0 += 32) {
    __syncthreads(); // buf[cur] staged-data visible; buf^1 free to overwrite
    if (k0 + 32 < K) {
      for (int m = 0; m < 2; ++m) {
        GLL16(A + (size_t)(bm + m * 64 + srow) * K + k0 + 32 + sck,
              (char*)As[cur ^ 1] + m * 4096 + w * 1024);
        GLL16(Bw + (size_t)(bn + m * 64 + srow) * K + k0 + 32 + sck,
              (char*)Bs[cur ^ 1] + m * 4096 + w * 1024);
      }
    }
    bf16x8 af[4], bf_[4];
    for (int m = 0; m < 4; ++m)
      af[m] = *(const bf16x8*)(As[cur] + (wm * 64 + m * 16 + c) * 32 + g * 8);
    for (int n = 0; n < 4; ++n)
      bf_[n] = *(const bf16x8*)(Bs[cur] + (wn * 64 + n * 16 + c) * 32 + g * 8);
    for (int m = 0; m < 4; ++m)
      for (int n = 0; n < 4; ++n)
        acc[m][n] = __builtin_amdgcn_mfma_f32_16x16x32_bf16(af[m], bf_[n],
                                                            acc[m][n], 0, 0, 0);
    cur ^= 1;
  }
  // D layout: row = 4*(lane>>4)+r, col = lane&15 (m89/m91 verified)
  for (int n = 0; n < 4; ++n) {
    const int col = bn + wn * 64 + n * 16 + c;
    const float bv = bias[col];
    for (int m = 0; m < 4; ++m) {
      if (MODE == 2) {
        // rows s = base..base+3 consecutive -> one 8B store into
        // vt[((b*16+h)*64+dh)][s], b = s>>11, h = col>>6, dh = col&63
        const int rs = bm + wm * 64 + m * 16 + g * 4; // 4-aligned
        u16x4 pk;
        for (int r = 0; r < 4; ++r) pk[r] = f2bf(acc[m][n][r] + bv);
        const size_t vrow = (size_t)((rs >> 11) * NHEADS + (col >> 6)) * DHEAD +
                            (col & 63);
        *(u16x4*)(ob + vrow * SEQ + (rs & 2047)) = pk;
      } else {
        for (int r = 0; r < 4; ++r) {
          const int row = bm + wm * 64 + m * 16 + g * 4 + r;
          float v = acc[m][n][r] + bv;
          if (MODE == 1)
            of[(size_t)row * N + col] = v;
          else
            ob[(size_t)row * N + col] = f2bf(v);
        }
      }
    }
  }
}

__global__ __launch_bounds__(256) void gemm_qkv(const u16* __restrict__ xb,
                                                const u16* __restrict__ wq,
                                                const u16* __restrict__ wk,
                                                const float* __restrict__ bq,
                                                const float* __restrict__ bk,
                                                u16* __restrict__ q,
                                                u16* __restrict__ k) {
  const int z = blockIdx.z;
  const u16* W = (z == 0) ? wq : wk;
  const float* bi = (z == 0) ? bq : bk;
  u16* o = (z == 0) ? q : k;
  gemm_core<0>(xb, W, bi, o, nullptr, blockIdx.y * 128, blockIdx.x * 128);
}

__global__ __launch_bounds__(256) void gemm_v(const u16* __restrict__ xb,
                                              const u16* __restrict__ wv,
                                              const float* __restrict__ bv,
                                              u16* __restrict__ vt) {
  gemm_core<2>(xb, wv, bv, vt, nullptr, blockIdx.y * 128, blockIdx.x * 128);
}

__global__ __launch_bounds__(256) void gemm_o(const u16* __restrict__ yb,
                                              const u16* __restrict__ wo,
                                              const float* __restrict__ bo,
                                              float* __restrict__ out) {
  gemm_core<1>(yb, wo, bo, nullptr, out, blockIdx.y * 128, blockIdx.x * 128);
}

// Flash attention w/ ALiBi + causal.
// One q-tile per block, grid 1024 -> 3 blocks/CU (48KB LDS). In-kernel swizzle
// puts all 32 blocks of a (b,h) on one XCD (T1: K/V tiles become L2-local) and
// dispatches longest blocks (qi=31) first so imbalance amortizes under
// oversubscription. Double-buffered K/V issue-before-compute prefetch,
// exp2-folded softmax, V from per-head transposed layout (swizzled b128 PV),
// row-sum of P via MFMA with all-ones B-frag (lacc) instead of shfl reduce.
__global__ __launch_bounds__(256) void attn(const u16* __restrict__ qb,
                                            const u16* __restrict__ kb,
                                            const u16* __restrict__ vt,
                                            u16* __restrict__ yb) {
  __shared__ __attribute__((aligned(16))) u16 Qs[64 * 64];
  __shared__ __attribute__((aligned(16))) u16 Ks[2][64 * 64];
  __shared__ __attribute__((aligned(16))) u16 Vs[2][64 * 64]; // [dh][k]
  __shared__ __attribute__((aligned(16))) u16 Ps[4 * 16 * 64];
  const int tx = threadIdx.x;
  const int w = tx >> 6, lane = tx & 63;
  const int c = lane & 15, g = lane >> 4;
  const int f = blockIdx.x;
  const int bh = (f & 7) * 4 + ((f >> 3) & 3); // 4 bh per XCD
  const int qi = NTILES - 1 - (f >> 5);        // longest first
  const int b = bh >> 4, h = bh & 15;
  const int q0 = qi * 64;
  const size_t rb = (size_t)b * SEQ;
  const size_t vtb = (size_t)bh * DHEAD; // vt row base for this (b,h)
  // base-2 folded constants: p = exp2(sc*S2 + slope2*(kidx-qidx) - m2)
  const float slope2 = exp2f(-0.5f * (float)(h + 1)) * 1.44269504f;
  const float S2 = 0.125f * 1.44269504f;

  const int strow = w * 8 + (lane >> 3); // staging row within 32-row half
  const int stck = lane & 7;             // staging chunk (8 elems of 8)

  // stage Q (swizzled) and K/V tile 0 into buf 0
  for (int m = 0; m < 2; ++m) {
    int row = m * 32 + strow;
    GLL16(qb + (rb + q0 + row) * D_MODEL + h * DHEAD + ((stck ^ (row & 7)) * 8),
          (char*)Qs + m * 4096 + w * 1024);
    GLL16(kb + (rb + row) * D_MODEL + h * DHEAD + ((stck ^ (row & 7)) * 8),
          (char*)Ks[0] + m * 4096 + w * 1024);
    GLL16(vt + (vtb + row) * SEQ + ((stck ^ (row & 7)) * 8),
          (char*)Vs[0] + m * 4096 + w * 1024);
  }

  float mrun[4];
  f32x4 acc[4], lacc;
  for (int r = 0; r < 4; ++r) mrun[r] = -1e30f;
  for (int d = 0; d < 4; ++d) acc[d] = {0.f, 0.f, 0.f, 0.f};
  lacc = {0.f, 0.f, 0.f, 0.f};
  bf16x8 ones;
  for (int j = 0; j < 8; ++j) ones[j] = (short)0x3F80; // bf16 1.0
  const float qrow[4] = {(float)(q0 + w * 16 + g * 4 + 0),
                         (float)(q0 + w * 16 + g * 4 + 1),
                         (float)(q0 + w * 16 + g * 4 + 2),
                         (float)(q0 + w * 16 + g * 4 + 3)};
  const int qrowi = q0 + w * 16 + g * 4;

  int cur = 0;
  for (int kt = 0; kt <= qi; ++kt) {
    __syncthreads(); // drains own GLL16s -> buf[cur] (and Qs) ready
    if (kt < qi) {   // prefetch next tile into buf^1; drain at NEXT barrier
      for (int m = 0; m < 2; ++m) {
        int row = m * 32 + strow;
        GLL16(kb + (rb + (kt + 1) * 64 + row) * D_MODEL + h * DHEAD +
                  ((stck ^ (row & 7)) * 8),
              (char*)Ks[cur ^ 1] + m * 4096 + w * 1024);
        GLL16(vt + (vtb + row) * SEQ + (kt + 1) * 64 +
                  ((stck ^ (row & 7)) * 8),
              (char*)Vs[cur ^ 1] + m * 4096 + w * 1024);
      }
    }

    // S = Q K^T
    bf16x8 aq[2];
    for (int ks = 0; ks < 2; ++ks)
      aq[ks] = *(const bf16x8*)((const char*)Qs + (w * 16 + c) * 128 +
                                ((ks * 64 + g * 16) ^ ((c & 7) << 4)));
    f32x4 sc[4];
    for (int n = 0; n < 4; ++n) {
      sc[n] = {0.f, 0.f, 0.f, 0.f};
      for (int ks = 0; ks < 2; ++ks) {
        bf16x8 bk = *(const bf16x8*)((const char*)Ks[cur] + (n * 16 + c) * 128 +
                                     ((ks * 64 + g * 16) ^ ((c & 7) << 4)));
        sc[n] = __builtin_amdgcn_mfma_f32_16x16x32_bf16(aq[ks], bk, sc[n], 0, 0, 0);
      }
    }

    // online softmax (base-2); lane holds rows 4g+r, cols n*16+c
    const int kbase = kt * 64 + c;
    const bool diag = (kt == qi); // only diagonal tile has masked entries
    float p[4][4];
    for (int r = 0; r < 4; ++r) {
      const float base = slope2 * ((float)kbase - qrow[r]);
      float srow_[4];
      float rmax = -1e30f;
      for (int n = 0; n < 4; ++n) {
        float s = fmaf(sc[n][r], S2, base + slope2 * (float)(n * 16));
        if (diag && (kbase + n * 16 > qrowi + r)) s = -1e30f;
        srow_[n] = s;
        rmax = fmaxf(rmax, s);
      }
      for (int off = 1; off < 16; off <<= 1)
        rmax = fmaxf(rmax, __shfl_xor(rmax, off));
      const float mn = fmaxf(mrun[r], rmax);
      const float corr = exp2f(mrun[r] - mn);
      mrun[r] = mn;
      for (int n = 0; n < 4; ++n) p[n][r] = exp2f(srow_[n] - mn);
      lacc[r] *= corr;
      for (int d = 0; d < 4; ++d) acc[d][r] *= corr;
    }

    // P (D-layout) -> LDS (bf16, row-XOR swizzle) -> A-frag layout
    for (int n = 0; n < 4; ++n)
      for (int r = 0; r < 4; ++r) {
        const int row = g * 4 + r;
        *(u16*)((char*)Ps + w * 2048 + row * 128 +
                (((n * 16 + c) * 2) ^ ((row & 7) << 4))) = f2bf(p[n][r]);
      }

    // O += P V ; lacc += P * ones (row-sum via MFMA, lands in same D layout)
    for (int ks = 0; ks < 2; ++ks) {
      bf16x8 pa = *(const bf16x8*)((const char*)Ps + w * 2048 + c * 128 +
                                   ((ks * 64 + g * 16) ^ ((c & 7) << 4)));
      for (int d = 0; d < 4; ++d) {
        bf16x8 vb_ = *(const bf16x8*)((const char*)Vs[cur] +
                                      (d * 16 + c) * 128 +
                                      ((ks * 64 + g * 16) ^ ((c & 7) << 4)));
        acc[d] = __builtin_amdgcn_mfma_f32_16x16x32_bf16(pa, vb_, acc[d], 0, 0, 0);
      }
      lacc = __builtin_amdgcn_mfma_f32_16x16x32_bf16(pa, ones, lacc, 0, 0, 0);
    }
    cur ^= 1;
  }

  for (int d = 0; d < 4; ++d)
    for (int r = 0; r < 4; ++r) {
      const int qlocal = w * 16 + g * 4 + r;
      float o = acc[d][r] / lacc[r];
      yb[(rb + q0 + qlocal) * D_MODEL + h * DHEAD + d * 16 + c] = f2bf(o);
    }
}

extern "C" void kernel_launch(void* const* d_in, const int* in_sizes, int n_in,
                              void* d_out, int out_size, void* d_ws,
                              size_t ws_size, hipStream_t stream) {
  const float* x = (const float*)d_in[0];
  const float* Wq = (const float*)d_in[1];
  const float* bq = (const float*)d_in[2];
  const float* Wk = (const float*)d_in[3];
  const float* bk = (const float*)d_in[4];
  const float* Wv = (const float*)d_in[5];
  const float* bv = (const float*)d_in[6];
  const float* Wo = (const float*)d_in[7];
  const float* bo = (const float*)d_in[8];
  float* out = (float*)d_out;

  // workspace layout (40 MB total; yb aliases xb — x dead after projections)
  char* ws = (char*)d_ws;
  u16* xb = (u16*)(ws + (size_t)0);          // 8 MB  4096x1024 bf16
  u16* wqb = (u16*)(ws + ((size_t)8 << 20)); // 2 MB each
  u16* wkb = (u16*)(ws + ((size_t)10 << 20));
  u16* wvb = (u16*)(ws + ((size_t)12 << 20));
  u16* wob = (u16*)(ws + ((size_t)14 << 20));
  u16* qb = (u16*)(ws + ((size_t)16 << 20)); // 8 MB each
  u16* kb = (u16*)(ws + ((size_t)24 << 20));
  u16* vtb = (u16*)(ws + ((size_t)32 << 20)); // 8 MB, [(b*16+h)*64+dh][2048]
  u16* yb = xb; // reuse: attn writes yb strictly after projections read xb

  castk<<<4096, 256, 0, stream>>>(x, xb, NROWS * D_MODEL / 4);
  castw<<<dim3(1024, 1, 4), 256, 0, stream>>>(Wq, Wk, Wv, Wo, wqb, wkb, wvb,
                                              wob);

  gemm_qkv<<<dim3(8, 32, 2), 256, 0, stream>>>(xb, wqb, wkb, bq, bk, qb, kb);
  gemm_v<<<dim3(8, 32, 1), 256, 0, stream>>>(xb, wvb, bv, vtb);
  attn<<<dim3(NTILES * NHEADS * BATCH, 1, 1), 256, 0, stream>>>(qb, kb, vtb, yb);
  gemm_o<<<dim3(8, 32, 1), 256, 0, stream>>>(yb, wob, bo, out);
}

// Round 9
// 210.756 us; speedup vs baseline: 1.4641x; 1.0822x over previous
//
#include <hip/hip_runtime.h>

typedef unsigned short u16;
typedef unsigned int u32;
typedef short bf16x8 __attribute__((ext_vector_type(8)));
typedef float f32x4 __attribute__((ext_vector_type(4)));
typedef u16 u16x4 __attribute__((ext_vector_type(4)));

#define D_MODEL 1024
#define NHEADS 16
#define DHEAD 64
#define BATCH 2
#define SEQ 2048
#define NROWS (BATCH * SEQ) /* 4096 */
#define NTILES (SEQ / 64)   /* 32 */

static __device__ __forceinline__ u16 f2bf(float f) {
  u32 x = __float_as_uint(f);
  x += 0x7fffu + ((x >> 16) & 1u); // RNE
  return (u16)(x >> 16);
}

// pack 2 f32 -> u32 of 2 bf16 (RNE), D[15:0]=lo, D[31:16]=hi
static __device__ __forceinline__ u32 cvtpk(float lo, float hi) {
  u32 r;
  asm("v_cvt_pk_bf16_f32 %0, %1, %2" : "=v"(r) : "v"(lo), "v"(hi));
  return r;
}

// global -> LDS direct (16B/lane). LDS dest is WAVE-UNIFORM base + lane*16 (m104/m108).
#define GLL16(gp, lp)                                             \
  __builtin_amdgcn_global_load_lds(                               \
      (const __attribute__((address_space(1))) u32*)(gp),         \
      (__attribute__((address_space(3))) u32*)(lp), 16, 0, 0)

__global__ __launch_bounds__(256) void castk(const float* __restrict__ in,
                                             u16* __restrict__ out, int n4) {
  int i = blockIdx.x * 256 + threadIdx.x;
  if (i >= n4) return;
  float4 v = ((const float4*)in)[i];
  u32 lo = (u32)f2bf(v.x) | ((u32)f2bf(v.y) << 16);
  u32 hi = (u32)f2bf(v.z) | ((u32)f2bf(v.w) << 16);
  ((uint2*)out)[i] = make_uint2(lo, hi);
}

// fused weight casts: z selects which W
__global__ __launch_bounds__(256) void castw(const float* __restrict__ w0,
                                             const float* __restrict__ w1,
                                             const float* __restrict__ w2,
                                             const float* __restrict__ w3,
                                             u16* __restrict__ o0,
                                             u16* __restrict__ o1,
                                             u16* __restrict__ o2,
                                             u16* __restrict__ o3) {
  const int z = blockIdx.z;
  const float* in = (z == 0) ? w0 : (z == 1) ? w1 : (z == 2) ? w2 : w3;
  u16* out = (z == 0) ? o0 : (z == 1) ? o1 : (z == 2) ? o2 : o3;
  int i = blockIdx.x * 256 + threadIdx.x;
  float4 v = ((const float4*)in)[i];
  u32 lo = (u32)f2bf(v.x) | ((u32)f2bf(v.y) << 16);
  u32 hi = (u32)f2bf(v.z) | ((u32)f2bf(v.w) << 16);
  ((uint2*)out)[i] = make_uint2(lo, hi);
}

// C[M,N] = A[M,K] * Bw[N,K]^T + bias ; all bf16 in, fp32 accum.
// 128x128 tile, BK=32, 4 waves (2x2), 4x4 16x16x32 MFMA per wave.
// 2-phase single-barrier prefetch double-buffer.
// MODE: 0 = bf16 row-major out, 1 = f32 row-major out,
//       2 = bf16 per-head TRANSPOSED out: vt[((b*16+h)*64+dh)][s] (for V)
template <int MODE>
__device__ __forceinline__ void gemm_core(const u16* __restrict__ A,
                                          const u16* __restrict__ Bw,
                                          const float* __restrict__ bias,
                                          u16* __restrict__ ob,
                                          float* __restrict__ of,
                                          int bm, int bn) {
  constexpr int K = 1024, N = 1024;
  __shared__ __attribute__((aligned(16))) u16 As[2][128 * 32];
  __shared__ __attribute__((aligned(16))) u16 Bs[2][128 * 32];
  const int tx = threadIdx.x;
  const int w = tx >> 6, lane = tx & 63;
  const int wm = w >> 1, wn = w & 1;
  const int c = lane & 15, g = lane >> 4;
  f32x4 acc[4][4];
  for (int m = 0; m < 4; ++m)
    for (int n = 0; n < 4; ++n) acc[m][n] = {0.f, 0.f, 0.f, 0.f};
  const int srow = w * 16 + (lane >> 2); // staging row within 64-row half
  const int sck = (lane & 3) * 8;        // staging K-chunk (8 elems)
  for (int m = 0; m < 2; ++m) {
    GLL16(A + (size_t)(bm + m * 64 + srow) * K + sck,
          (char*)As[0] + m * 4096 + w * 1024);
    GLL16(Bw + (size_t)(bn + m * 64 + srow) * K + sck,
          (char*)Bs[0] + m * 4096 + w * 1024);
  }
  int cur = 0;
  for (int k0 = 0; k0 < K; k0 += 32) {
    __syncthreads(); // buf[cur] staged-data visible; buf^1 free to overwrite
    if (k0 + 32 < K) {
      for (int m = 0; m < 2; ++m) {
        GLL16(A + (size_t)(bm + m * 64 + srow) * K + k0 + 32 + sck,
              (char*)As[cur ^ 1] + m * 4096 + w * 1024);
        GLL16(Bw + (size_t)(bn + m * 64 + srow) * K + k0 + 32 + sck,
              (char*)Bs[cur ^ 1] + m * 4096 + w * 1024);
      }
    }
    bf16x8 af[4], bf_[4];
    for (int m = 0; m < 4; ++m)
      af[m] = *(const bf16x8*)(As[cur] + (wm * 64 + m * 16 + c) * 32 + g * 8);
    for (int n = 0; n < 4; ++n)
      bf_[n] = *(const bf16x8*)(Bs[cur] + (wn * 64 + n * 16 + c) * 32 + g * 8);
    for (int m = 0; m < 4; ++m)
      for (int n = 0; n < 4; ++n)
        acc[m][n] = __builtin_amdgcn_mfma_f32_16x16x32_bf16(af[m], bf_[n],
                                                            acc[m][n], 0, 0, 0);
    cur ^= 1;
  }
  // D layout: row = 4*(lane>>4)+r, col = lane&15 (m89/m91 verified)
  for (int n = 0; n < 4; ++n) {
    const int col = bn + wn * 64 + n * 16 + c;
    const float bv = bias[col];
    for (int m = 0; m < 4; ++m) {
      if (MODE == 2) {
        const int rs = bm + wm * 64 + m * 16 + g * 4; // 4-aligned
        u16x4 pk;
        for (int r = 0; r < 4; ++r) pk[r] = f2bf(acc[m][n][r] + bv);
        const size_t vrow = (size_t)((rs >> 11) * NHEADS + (col >> 6)) * DHEAD +
                            (col & 63);
        *(u16x4*)(ob + vrow * SEQ + (rs & 2047)) = pk;
      } else {
        for (int r = 0; r < 4; ++r) {
          const int row = bm + wm * 64 + m * 16 + g * 4 + r;
          float v = acc[m][n][r] + bv;
          if (MODE == 1)
            of[(size_t)row * N + col] = v;
          else
            ob[(size_t)row * N + col] = f2bf(v);
        }
      }
    }
  }
}

// merged Q/K/V projections: z=0 Q, z=1 K, z=2 V(transposed out) — 768 blocks
__global__ __launch_bounds__(256) void gemm_qkv(const u16* __restrict__ xb,
                                                const u16* __restrict__ wq,
                                                const u16* __restrict__ wk,
                                                const u16* __restrict__ wv,
                                                const float* __restrict__ bq,
                                                const float* __restrict__ bk,
                                                const float* __restrict__ bv,
                                                u16* __restrict__ q,
                                                u16* __restrict__ k,
                                                u16* __restrict__ vt) {
  const int z = blockIdx.z;
  if (z == 2)
    gemm_core<2>(xb, wv, bv, vt, nullptr, blockIdx.y * 128, blockIdx.x * 128);
  else
    gemm_core<0>(xb, z ? wk : wq, z ? bk : bq, z ? k : q, nullptr,
                 blockIdx.y * 128, blockIdx.x * 128);
}

__global__ __launch_bounds__(256) void gemm_o(const u16* __restrict__ yb,
                                              const u16* __restrict__ wo,
                                              const float* __restrict__ bo,
                                              float* __restrict__ out) {
  gemm_core<1>(yb, wo, bo, nullptr, out, blockIdx.y * 128, blockIdx.x * 128);
}

// Flash attention w/ ALiBi + causal — swapped-QK^T in-register softmax.
// mfma(K,Q) puts S^T in D layout: lane (c,g) holds 16 S values all for q=c,
// k = kt*64 + n*16 + 4g + r (r spans consecutive k -> cvt_pk packing).
// Row-max: 15 in-lane max + 2 shfl_xor. corr: ONE exp2/lane; redistributed to
// acc rows (q=4g+r) via 4 bpermutes. P -> LDS: 4x ds_write_b64 (swizzled),
// read back as A-frags (byte-identical pattern to round-8). Q frags direct
// from global (no Qs -> LDS 40KB -> 4 blocks/CU). XCD swizzle, K/V prefetch
// double-buffer, lsum via ones-MFMA kept from round 8.
__global__ __launch_bounds__(256) void attn(const u16* __restrict__ qb,
                                            const u16* __restrict__ kb,
                                            const u16* __restrict__ vt,
                                            u16* __restrict__ yb) {
  __shared__ __attribute__((aligned(16))) u16 Ks[2][64 * 64];
  __shared__ __attribute__((aligned(16))) u16 Vs[2][64 * 64]; // [dh][k]
  __shared__ __attribute__((aligned(16))) u16 Ps[4 * 16 * 64]; // row=q(c), 64 k
  const int tx = threadIdx.x;
  const int w = tx >> 6, lane = tx & 63;
  const int c = lane & 15, g = lane >> 4;
  const int f = blockIdx.x;
  const int bh = (f & 7) * 4 + ((f >> 3) & 3); // 4 bh per XCD
  const int qi = NTILES - 1 - (f >> 5);        // longest first
  const int b = bh >> 4, h = bh & 15;
  const int q0 = qi * 64;
  const size_t rb = (size_t)b * SEQ;
  const size_t vtb = (size_t)bh * DHEAD; // vt row base for this (b,h)
  // base-2 folded constants: p = exp2(sc*S2 + slope2*(kidx-qidx) - m2)
  const float slope2 = exp2f(-0.5f * (float)(h + 1)) * 1.44269504f;
  const float S2 = 0.125f * 1.44269504f;

  const int strow = w * 8 + (lane >> 3); // staging row within 32-row half
  const int stck = lane & 7;             // staging chunk (8 elems of 8)

  // Q fragments direct from global (B-operand; same per-lane layout as A)
  const u16* qp = qb + (rb + q0 + w * 16 + c) * D_MODEL + h * DHEAD;
  bf16x8 aq[2];
  aq[0] = *(const bf16x8*)(qp + g * 8);
  aq[1] = *(const bf16x8*)(qp + 32 + g * 8);

  // stage K/V tile 0 into buf 0
  for (int m = 0; m < 2; ++m) {
    int row = m * 32 + strow;
    GLL16(kb + (rb + row) * D_MODEL + h * DHEAD + ((stck ^ (row & 7)) * 8),
          (char*)Ks[0] + m * 4096 + w * 1024);
    GLL16(vt + (vtb + row) * SEQ + ((stck ^ (row & 7)) * 8),
          (char*)Vs[0] + m * 4096 + w * 1024);
  }

  float mrun = -1e30f; // per-lane running max for q = q0 + w*16 + c
  f32x4 acc[4], lacc;
  for (int d = 0; d < 4; ++d) acc[d] = {0.f, 0.f, 0.f, 0.f};
  lacc = {0.f, 0.f, 0.f, 0.f};
  bf16x8 ones;
  for (int j = 0; j < 8; ++j) ones[j] = (short)0x3F80; // bf16 1.0
  const int qidx = q0 + w * 16 + c;
  const float alibase = slope2 * (float)(4 * g - qidx);
  const int swz = (c & 7) << 4;

  int cur = 0;
  for (int kt = 0; kt <= qi; ++kt) {
    __syncthreads(); // drains own GLL16s -> buf[cur] ready
    if (kt < qi) {   // prefetch next tile into buf^1; drain at NEXT barrier
      for (int m = 0; m < 2; ++m) {
        int row = m * 32 + strow;
        GLL16(kb + (rb + (kt + 1) * 64 + row) * D_MODEL + h * DHEAD +
                  ((stck ^ (row & 7)) * 8),
              (char*)Ks[cur ^ 1] + m * 4096 + w * 1024);
        GLL16(vt + (vtb + row) * SEQ + (kt + 1) * 64 +
                  ((stck ^ (row & 7)) * 8),
              (char*)Vs[cur ^ 1] + m * 4096 + w * 1024);
      }
    }

    // S^T = K Q^T : mfma(bk, aq) -> D[k-row][q-col], lane holds q=c
    f32x4 sc[4];
    for (int n = 0; n < 4; ++n) {
      sc[n] = {0.f, 0.f, 0.f, 0.f};
      for (int ks = 0; ks < 2; ++ks) {
        bf16x8 bk = *(const bf16x8*)((const char*)Ks[cur] + (n * 16 + c) * 128 +
                                     ((ks * 64 + g * 16) ^ swz));
        sc[n] = __builtin_amdgcn_mfma_f32_16x16x32_bf16(bk, aq[ks], sc[n], 0, 0, 0);
      }
    }

    // softmax (base-2), all 16 values belong to q=c: k = kt*64 + n*16 + 4g + r
    const bool diag = (kt == qi);
    const int kb0 = kt * 64 + 4 * g;
    const float alikt = alibase + slope2 * (float)(kt * 64);
    float p[4][4];
    float rmax = -1e30f;
    for (int n = 0; n < 4; ++n) {
      const float tn = alikt + slope2 * (float)(n * 16);
      for (int r = 0; r < 4; ++r) {
        float s = fmaf(sc[n][r], S2, fmaf((float)r, slope2, tn));
        if (diag && (kb0 + n * 16 + r > qidx)) s = -1e30f;
        p[n][r] = s;
        rmax = fmaxf(rmax, s);
      }
    }
    rmax = fmaxf(rmax, __shfl_xor(rmax, 16));
    rmax = fmaxf(rmax, __shfl_xor(rmax, 32));
    const float mn = fmaxf(mrun, rmax);
    const float corr = exp2f(mrun - mn);
    mrun = mn;
    // P = exp2(s - mn); pack pairs (consecutive k) and store 4x b64
    for (int n = 0; n < 4; ++n) {
      u32 lo = cvtpk(exp2f(p[n][0] - mn), exp2f(p[n][1] - mn));
      u32 hi = cvtpk(exp2f(p[n][2] - mn), exp2f(p[n][3] - mn));
      *(uint2*)((char*)Ps + w * 2048 + c * 128 + ((n * 32 + 8 * g) ^ swz)) =
          make_uint2(lo, hi);
    }
    // redistribute corr to acc-row owners: acc reg r <-> q-row 4g+r (lane c'=4g+r)
    float corr_row[4];
    for (int r = 0; r < 4; ++r) corr_row[r] = __shfl(corr, 4 * g + r);
    for (int r = 0; r < 4; ++r) {
      lacc[r] *= corr_row[r];
      for (int d = 0; d < 4; ++d) acc[d][r] *= corr_row[r];
    }

    // O += P V ; lacc += P * ones  (same-wave DS pipe orders Ps write->read)
    for (int ks = 0; ks < 2; ++ks) {
      bf16x8 pa = *(const bf16x8*)((const char*)Ps + w * 2048 + c * 128 +
                                   ((ks * 64 + g * 16) ^ swz));
      for (int d = 0; d < 4; ++d) {
        bf16x8 vb_ = *(const bf16x8*)((const char*)Vs[cur] +
                                      (d * 16 + c) * 128 +
                                      ((ks * 64 + g * 16) ^ swz));
        acc[d] = __builtin_amdgcn_mfma_f32_16x16x32_bf16(pa, vb_, acc[d], 0, 0, 0);
      }
      lacc = __builtin_amdgcn_mfma_f32_16x16x32_bf16(pa, ones, lacc, 0, 0, 0);
    }
    cur ^= 1;
  }

  for (int d = 0; d < 4; ++d)
    for (int r = 0; r < 4; ++r) {
      const int qlocal = w * 16 + g * 4 + r;
      float o = acc[d][r] / lacc[r];
      yb[(rb + q0 + qlocal) * D_MODEL + h * DHEAD + d * 16 + c] = f2bf(o);
    }
}

extern "C" void kernel_launch(void* const* d_in, const int* in_sizes, int n_in,
                              void* d_out, int out_size, void* d_ws,
                              size_t ws_size, hipStream_t stream) {
  const float* x = (const float*)d_in[0];
  const float* Wq = (const float*)d_in[1];
  const float* bq = (const float*)d_in[2];
  const float* Wk = (const float*)d_in[3];
  const float* bk = (const float*)d_in[4];
  const float* Wv = (const float*)d_in[5];
  const float* bv = (const float*)d_in[6];
  const float* Wo = (const float*)d_in[7];
  const float* bo = (const float*)d_in[8];
  float* out = (float*)d_out;

  // workspace layout (40 MB total; yb aliases xb — x dead after projections)
  char* ws = (char*)d_ws;
  u16* xb = (u16*)(ws + (size_t)0);          // 8 MB  4096x1024 bf16
  u16* wqb = (u16*)(ws + ((size_t)8 << 20)); // 2 MB each
  u16* wkb = (u16*)(ws + ((size_t)10 << 20));
  u16* wvb = (u16*)(ws + ((size_t)12 << 20));
  u16* wob = (u16*)(ws + ((size_t)14 << 20));
  u16* qb = (u16*)(ws + ((size_t)16 << 20)); // 8 MB each
  u16* kb = (u16*)(ws + ((size_t)24 << 20));
  u16* vtb = (u16*)(ws + ((size_t)32 << 20)); // 8 MB, [(b*16+h)*64+dh][2048]
  u16* yb = xb; // reuse: attn writes yb strictly after projections read xb

  castk<<<4096, 256, 0, stream>>>(x, xb, NROWS * D_MODEL / 4);
  castw<<<dim3(1024, 1, 4), 256, 0, stream>>>(Wq, Wk, Wv, Wo, wqb, wkb, wvb,
                                              wob);

  gemm_qkv<<<dim3(8, 32, 3), 256, 0, stream>>>(xb, wqb, wkb, wvb, bq, bk, bv,
                                               qb, kb, vtb);
  attn<<<dim3(NTILES * NHEADS * BATCH, 1, 1), 256, 0, stream>>>(qb, kb, vtb, yb);
  gemm_o<<<dim3(8, 32, 1), 256, 0, stream>>>(yb, wob, bo, out);
}